// Round 3
// baseline (7148.475 us; speedup 1.0000x reference)
//
#include <hip/hip_runtime.h>

#define B_    64
#define T_    1024
#define IN_   64
#define H_    512
#define OUT_  64
#define SLOTS 8
#define BH    (64*512)   // elements per h slot
#define NWG   130

typedef _Float16 f16;
typedef _Float16 half8 __attribute__((ext_vector_type(8)));
typedef float    floatx4 __attribute__((ext_vector_type(4)));
typedef unsigned int u32;
typedef unsigned long long u64;

#define MFMA16(a,b,c) __builtin_amdgcn_mfma_f32_16x16x32_f16((a),(b),(c),0,0,0)

// LDS layout (108544 B, 1 WG/CU)  -- R5 layout
#define XS_OFF   0        // 8KB: L1 x-stage; also h-publish buffer (all stages)
#define H1S_OFF  8192     // 32KB: recurrent/h1 stage
#define H2S_OFF  40960    // 32KB: h2 stage (L2 pass B)
#define RED_OFF  73728    // 32KB: 4 kq-regions x 8KB partial-sum
#define CC_OFF   106496   // 2KB c-state

__device__ __forceinline__ float sigmoidf_(float x) {
    return 1.0f / (1.0f + __expf(-x));
}
__device__ __forceinline__ float tanhf_(float x) {
    float ax = fabsf(x);
    float e  = __expf(-2.0f * ax);
    float t  = (1.0f - e) / (1.0f + e);
    return x >= 0.0f ? t : -t;
}

// Flags: agent-scope RMW + agent-scope poll (proven R2/R5).
__device__ __forceinline__ void wait_ge(u32* p, u32 v) {
    while (__hip_atomic_load(p, __ATOMIC_RELAXED, __HIP_MEMORY_SCOPE_AGENT) < v)
        __builtin_amdgcn_s_sleep(1);
}
__device__ __forceinline__ void flag_add(u32* p) {
    __hip_atomic_fetch_add(p, 1u, __ATOMIC_RELAXED, __HIP_MEMORY_SCOPE_AGENT);
}
// Data reads: system-scope relaxed load (sc0+sc1, reads IF$ coherence point). Proven R5.
__device__ __forceinline__ u64 aload8(const f16* p) {
    return __hip_atomic_load((const u64*)p, __ATOMIC_RELAXED, __HIP_MEMORY_SCOPE_SYSTEM);
}
// Data publish: RETURNING system-scope exchange; vmcnt retires only after the
// IF$ round-trip, so the pre-flag __syncthreads orders data before flag. Proven R5.
__device__ __forceinline__ void apub8(f16* p, u64 v) {
    u64 old = __hip_atomic_exchange((u64*)p, v, __ATOMIC_RELAXED, __HIP_MEMORY_SCOPE_SYSTEM);
    asm volatile("" : : "v"(old));
}

// ---------------- prep kernels (weights -> fp16 fragment-linear) ----------------
__global__ void pack_w1(const float* __restrict__ Wih, const float* __restrict__ Whh,
                        f16* __restrict__ Wp) {
    int idx = blockIdx.x * 256 + threadIdx.x;
    if (idx >= 4*32*18*512) return;
    int j    = idx & 7;
    int lane = (idx >> 3) & 63;
    int kt   = (idx >> 9) % 18;
    int r    = (idx >> 9) / 18;
    int jt   = r & 31;
    int g    = r >> 5;
    int n = g*512 + jt*16 + (lane & 15);
    int k = kt*32 + (lane >> 4)*8 + j;
    float v = (k < 64) ? Wih[n*64 + k] : Whh[n*512 + (k - 64)];
    Wp[idx] = (f16)v;
}

__global__ void pack_w2(const float* __restrict__ Wih, const float* __restrict__ Whh,
                        f16* __restrict__ Wp) {
    int idx = blockIdx.x * 256 + threadIdx.x;
    if (idx >= 4*32*32*512) return;
    int j    = idx & 7;
    int lane = (idx >> 3) & 63;
    int kt   = (idx >> 9) & 31;
    int r    = idx >> 14;
    int jt   = r & 31;
    int g    = r >> 5;
    int n = g*512 + jt*16 + (lane & 15);
    int k = kt*32 + (lane >> 4)*8 + j;
    float v = (k < 512) ? Wih[n*512 + k] : Whh[n*512 + (k - 512)];
    Wp[idx] = (f16)v;
}

__global__ void pack_wo(const float* __restrict__ Wout, f16* __restrict__ Wp) {
    int idx = blockIdx.x * 256 + threadIdx.x;
    if (idx >= 4*16*512) return;
    int j    = idx & 7;
    int lane = (idx >> 3) & 63;
    int kt   = (idx >> 9) & 15;
    int nt   = idx >> 13;
    int n = nt*16 + (lane & 15);
    int k = kt*32 + (lane >> 4)*8 + j;
    Wp[idx] = (f16)Wout[n*512 + k];
}

__global__ void bias_sum(const float* __restrict__ a1, const float* __restrict__ b1,
                         const float* __restrict__ a2, const float* __restrict__ b2,
                         float* __restrict__ s1, float* __restrict__ s2) {
    int i = blockIdx.x * 256 + threadIdx.x;
    if (i >= 2048) return;
    s1[i] = a1[i] + b1[i];
    s2[i] = a2[i] + b2[i];
}

// ---------------- persistent self-timed kernel ----------------
// WG 0..63:   layer1 (jt = wg&31, bhalf = wg>>5); waves gp=w&1, kq=w>>1 (K-slice)
// WG 64..127: layer2 (v=wg-64: jt=v&31, bhalf=v>>5); same wave split
// WG 128..129: head (bhalf = wg-128)
// h buffers: 8 slots (slot = t&7).
// R8: L1 and head are EXACTLY R5. L2 is software-pipelined on h1:
//  - h1[t2+1] staging loads issue concurrently with the h2[t2] publish
//    exchanges (both drain under the same pre-flag barrier), so staging
//    hides in the publish round trip;
//  - pass A runs at loop top from already-staged LDS;
//  - a2[t2-1] poll stays AFTER pass A (R5-proven skew overlap);
//  - a1[t2+1] poll sits after pointwise (L1 runs ahead; cannot block the
//    a2-gated prefix);
//  - 2 fewer barriers per L2 iteration.
__global__ __launch_bounds__(512, 1) void lstm_persist(
    const float* __restrict__ x,
    const f16*  __restrict__ W1p,
    const f16*  __restrict__ W2p,
    const f16*  __restrict__ Wop,
    const float* __restrict__ bs1,
    const float* __restrict__ bs2,
    const float* __restrict__ bout,
    f16*  __restrict__ h1buf,   // [8][64][512] fp16
    f16*  __restrict__ h2buf,   // [8][64][512] fp16
    float* __restrict__ y,
    u32*  __restrict__ arr1,    // [2][1024]
    u32*  __restrict__ arr2,    // [2][1024]
    u32*  __restrict__ arrH)    // [2][1024]
{
    __shared__ __align__(16) char smem[108544];
    float* RED = (float*)(smem + RED_OFF);
    float* CC  = (float*)(smem + CC_OFF);

    const int wg   = blockIdx.x;
    const int tid  = threadIdx.x;
    const int lane = tid & 63;
    const int w    = tid >> 6;
    const int col  = lane & 15;
    const int quad = lane >> 4;

    if (wg < 64) {
        // ================= layer 1 (exactly R5) =================
        const int jt = wg & 31, bhalf = wg >> 5;
        const int gp = w & 1, kq = w >> 1;
        half8 wrx[2];
        half8 wrh[2][4];
        if (kq < 2) {
            #pragma unroll
            for (int gi = 0; gi < 2; ++gi)
                wrx[gi] = *(const half8*)(W1p + ((size_t)(((gp*2+gi)*32 + jt)*18 + kq)*64 + lane)*8);
        }
        #pragma unroll
        for (int gi = 0; gi < 2; ++gi)
            #pragma unroll
            for (int k = 0; k < 4; ++k) {
                const int kt = 2 + kq*4 + k;
                wrh[gi][k] = *(const half8*)(W1p + ((size_t)(((gp*2+gi)*32 + jt)*18 + kt)*64 + lane)*8);
            }
        float bsr[4];
        #pragma unroll
        for (int g = 0; g < 4; ++g) bsr[g] = bs1[g*512 + jt*16 + (tid & 15)];
        CC[tid] = 0.f;

        u32* a1 = arr1 + bhalf*1024;
        u32* a2 = arr2 + bhalf*1024;

        for (int t = 0; t < T_; ++t) {
            const int sR = (t + SLOTS - 1) & (SLOTS-1);
            const int sW = t & (SLOTS-1);
            {   // stage x_t (plain loads) -- overlaps the polls below
                const int lb = tid >> 4, kc4 = tid & 15;
                const float* src = x + ((size_t)(bhalf*32 + lb)*T_ + t)*(size_t)IN_ + ((kc4 ^ (lb & 7)) * 4);
                *(float4*)(smem + XS_OFF + tid*16) = *(const float4*)src;
            }
            if (tid == 0) {
                if (t >= 1)     wait_ge(a1 + (t-1), 32u);      // recurrence
                if (t >= SLOTS) wait_ge(a2 + (t-SLOTS), 32u);  // slot reuse backpressure
            }
            __syncthreads();
            #pragma unroll
            for (int i = 0; i < 8; ++i) {   // stage h1[t-1]
                const int g2 = i*512 + tid;
                const int lb = g2 >> 7, r = g2 & 127, q = r >> 1, hf = r & 1;
                u64 v = aload8(h1buf + (size_t)sR*BH + (size_t)(bhalf*32 + lb)*H_ + ((q ^ (lb & 7))*8 + hf*4));
                *(u64*)(smem + H1S_OFF + (size_t)(lb*64 + q)*16 + hf*8) = v;
            }
            __syncthreads();
            floatx4 acc[2][2] = {{{0.f,0.f,0.f,0.f},{0.f,0.f,0.f,0.f}},
                                 {{0.f,0.f,0.f,0.f},{0.f,0.f,0.f,0.f}}};
            #pragma unroll
            for (int m = 0; m < 2; ++m) {
                const int lb_a = m*16 + col, sw = lb_a & 7;
                if (kq < 2) {   // x-part: this kq's 32-col tile
                    const int fg = kq*8 + quad*2;
                    float4 u = *(const float4*)(smem + XS_OFF + ((size_t)lb_a*16 + (fg ^ sw))*16);
                    float4 v = *(const float4*)(smem + XS_OFF + ((size_t)lb_a*16 + ((fg+1) ^ sw))*16);
                    half8 a = (half8){(f16)u.x,(f16)u.y,(f16)u.z,(f16)u.w,
                                      (f16)v.x,(f16)v.y,(f16)v.z,(f16)v.w};
                    acc[0][m] = MFMA16(a, wrx[0], acc[0][m]);
                    acc[1][m] = MFMA16(a, wrx[1], acc[1][m]);
                }
                #pragma unroll
                for (int k = 0; k < 4; ++k) {
                    const int kc = kq*16 + k*4 + quad;
                    half8 a = *(const half8*)(smem + H1S_OFF + ((size_t)lb_a*64 + (kc ^ sw))*16);
                    acc[0][m] = MFMA16(a, wrh[0][k], acc[0][m]);
                    acc[1][m] = MFMA16(a, wrh[1][k], acc[1][m]);
                }
            }
            #pragma unroll
            for (int gi = 0; gi < 2; ++gi) {
                const int g = gp*2 + gi;
                #pragma unroll
                for (int m = 0; m < 2; ++m)
                    #pragma unroll
                    for (int r = 0; r < 4; ++r)
                        RED[kq*2048 + g*512 + (m*16 + quad*4 + r)*16 + col] = acc[gi][m][r];
            }
            __syncthreads();
            {   // 4-way kq sum + pointwise
                float gt[4];
                #pragma unroll
                for (int g = 0; g < 4; ++g)
                    gt[g] = RED[       g*512 + tid] + RED[2048 + g*512 + tid]
                          + RED[4096 + g*512 + tid] + RED[6144 + g*512 + tid] + bsr[g];
                const float i_ = sigmoidf_(gt[0]);
                const float f_ = sigmoidf_(gt[1]);
                const float g_ = tanhf_(gt[2]);
                const float o_ = sigmoidf_(gt[3]);
                const float cn = f_ * CC[tid] + i_ * g_;
                CC[tid] = cn;
                ((f16*)(smem + XS_OFF))[tid] = (f16)(o_ * tanhf_(cn));
            }
            __syncthreads();
            if (tid < 128) {   // publish 1KB slice via returning exchanges
                const int b = tid >> 2, jq = tid & 3;
                u64 v = *(const u64*)(smem + XS_OFF + (size_t)(b*16 + jq*4)*2);
                apub8(h1buf + (size_t)sW*BH + (size_t)(bhalf*32 + b)*H_ + jt*16 + jq*4, v);
            }
            __syncthreads();
            if (tid == 0) flag_add(a1 + t);
        }
    } else if (wg < 128) {
        // ================= layer 2 (h1-pipelined) =================
        const int v = wg - 64;
        const int jt = v & 31, bhalf = v >> 5;
        const int gp = w & 1, kq = w >> 1;
        half8 wrA[2][4], wrB[2][4];
        #pragma unroll
        for (int gi = 0; gi < 2; ++gi)
            #pragma unroll
            for (int k = 0; k < 4; ++k) {
                const int ktA = kq*4 + k;        // h1 half (K 0..511)
                const int ktB = 16 + kq*4 + k;   // h2 half (K 512..1023)
                wrA[gi][k] = *(const half8*)(W2p + ((size_t)(((gp*2+gi)*32 + jt)*32 + ktA)*64 + lane)*8);
                wrB[gi][k] = *(const half8*)(W2p + ((size_t)(((gp*2+gi)*32 + jt)*32 + ktB)*64 + lane)*8);
            }
        float bsr[4];
        #pragma unroll
        for (int g = 0; g < 4; ++g) bsr[g] = bs2[g*512 + jt*16 + (tid & 15)];
        CC[tid] = 0.f;

        u32* a1 = arr1 + bhalf*1024;
        u32* a2 = arr2 + bhalf*1024;
        u32* aH = arrH + bhalf*1024;

        // ---- prologue: stage h1[0] into H1S ----
        if (tid == 0) wait_ge(a1 + 0, 32u);
        __syncthreads();
        #pragma unroll
        for (int i = 0; i < 8; ++i) {
            const int g2 = i*512 + tid;
            const int lb = g2 >> 7, r = g2 & 127, q = r >> 1, hf = r & 1;
            u64 vv = aload8(h1buf + (size_t)(bhalf*32 + lb)*H_ + ((q ^ (lb & 7))*8 + hf*4));
            *(u64*)(smem + H1S_OFF + (size_t)(lb*64 + q)*16 + hf*8) = vv;
        }
        __syncthreads();

        for (int t2 = 0; t2 < T_; ++t2) {
            const int sRd  = (t2 + SLOTS - 1) & (SLOTS-1);
            const int sW   = t2 & (SLOTS-1);
            const int sH1n = (t2 + 1) & (SLOTS-1);
            floatx4 acc[2][2] = {{{0.f,0.f,0.f,0.f},{0.f,0.f,0.f,0.f}},
                                 {{0.f,0.f,0.f,0.f},{0.f,0.f,0.f,0.f}}};
            // ---- pass A (h1[t2] already staged) ----
            #pragma unroll
            for (int m = 0; m < 2; ++m) {
                const int lb_a = m*16 + col, sw = lb_a & 7;
                #pragma unroll
                for (int k = 0; k < 4; ++k) {
                    const int kc = kq*16 + k*4 + quad;
                    half8 a = *(const half8*)(smem + H1S_OFF + ((size_t)lb_a*64 + (kc ^ sw))*16);
                    acc[0][m] = MFMA16(a, wrA[0][k], acc[0][m]);
                    acc[1][m] = MFMA16(a, wrA[1][k], acc[1][m]);
                }
            }
            // serial polls on tid0 after pass A (R5-proven skew overlap)
            if (tid == 0) {
                if (t2 >= 1)     wait_ge(a2 + (t2-1), 32u);    // recurrence
                if (t2 >= SLOTS) wait_ge(aH + (t2-SLOTS), 1u); // head consumed h2[t2-8]
            }
            __syncthreads();
            #pragma unroll
            for (int i = 0; i < 8; ++i) {   // stage h2[t2-1]
                const int g2 = i*512 + tid;
                const int lb = g2 >> 7, r = g2 & 127, q = r >> 1, hf = r & 1;
                u64 vv = aload8(h2buf + (size_t)sRd*BH + (size_t)(bhalf*32 + lb)*H_ + ((q ^ (lb & 7))*8 + hf*4));
                *(u64*)(smem + H2S_OFF + (size_t)(lb*64 + q)*16 + hf*8) = vv;
            }
            __syncthreads();
            // ---- pass B (h2 half) ----
            #pragma unroll
            for (int m = 0; m < 2; ++m) {
                const int lb_a = m*16 + col, sw = lb_a & 7;
                #pragma unroll
                for (int k = 0; k < 4; ++k) {
                    const int kc = kq*16 + k*4 + quad;
                    half8 a = *(const half8*)(smem + H2S_OFF + ((size_t)lb_a*64 + (kc ^ sw))*16);
                    acc[0][m] = MFMA16(a, wrB[0][k], acc[0][m]);
                    acc[1][m] = MFMA16(a, wrB[1][k], acc[1][m]);
                }
            }
            #pragma unroll
            for (int gi = 0; gi < 2; ++gi) {
                const int g = gp*2 + gi;
                #pragma unroll
                for (int m = 0; m < 2; ++m)
                    #pragma unroll
                    for (int r = 0; r < 4; ++r)
                        RED[kq*2048 + g*512 + (m*16 + quad*4 + r)*16 + col] = acc[gi][m][r];
            }
            __syncthreads();
            {   // 4-way kq sum + pointwise
                float gt[4];
                #pragma unroll
                for (int g = 0; g < 4; ++g)
                    gt[g] = RED[       g*512 + tid] + RED[2048 + g*512 + tid]
                          + RED[4096 + g*512 + tid] + RED[6144 + g*512 + tid] + bsr[g];
                const float i_ = sigmoidf_(gt[0]);
                const float f_ = sigmoidf_(gt[1]);
                const float g_ = tanhf_(gt[2]);
                const float o_ = sigmoidf_(gt[3]);
                const float cn = f_ * CC[tid] + i_ * g_;
                CC[tid] = cn;
                ((f16*)(smem + XS_OFF))[tid] = (f16)(o_ * tanhf_(cn));
            }
            // a1[t2+1] poll: L1 runs ahead (8-slot buffer), nearly always
            // satisfied; placed here so it cannot block the a2-gated prefix.
            if (tid == 0 && t2 + 1 < T_) wait_ge(a1 + (t2+1), 32u);
            __syncthreads();
            // publish h2[t2] (tid<128) CONCURRENT with staging h1[t2+1] (all
            // threads) -- both retire under the same pre-flag barrier drain.
            if (tid < 128) {
                const int b = tid >> 2, jq = tid & 3;
                u64 vv = *(const u64*)(smem + XS_OFF + (size_t)(b*16 + jq*4)*2);
                apub8(h2buf + (size_t)sW*BH + (size_t)(bhalf*32 + b)*H_ + jt*16 + jq*4, vv);
            }
            if (t2 + 1 < T_) {
                #pragma unroll
                for (int i = 0; i < 8; ++i) {   // stage h1[t2+1]
                    const int g2 = i*512 + tid;
                    const int lb = g2 >> 7, r = g2 & 127, q = r >> 1, hf = r & 1;
                    u64 vv = aload8(h1buf + (size_t)sH1n*BH + (size_t)(bhalf*32 + lb)*H_ + ((q ^ (lb & 7))*8 + hf*4));
                    *(u64*)(smem + H1S_OFF + (size_t)(lb*64 + q)*16 + hf*8) = vv;
                }
            }
            __syncthreads();   // drains exchanges + staging before flag
            if (tid == 0) flag_add(a2 + t2);
        }
    } else {
        // ================= head (exactly R5) =================
        const int bhalf = wg - 128;
        const int nt = w & 3, kh = w >> 2;
        half8 wr[8];
        #pragma unroll
        for (int k = 0; k < 8; ++k) {
            const int kt = kh*8 + k;
            wr[k] = *(const half8*)(Wop + ((size_t)(nt*16 + kt)*64 + lane)*8);
        }
        const float boutr = bout[nt*16 + col];
        u32* a2 = arr2 + bhalf*1024;
        u32* aH = arrH + bhalf*1024;
        const int lb0 = col, lb1 = 16 + col;
        const int swz = col & 7;

        for (int t3 = 0; t3 < T_; ++t3) {
            const int sH = t3 & (SLOTS-1);
            if (tid == 0) wait_ge(a2 + t3, 32u);
            __syncthreads();
            #pragma unroll
            for (int i = 0; i < 8; ++i) {   // stage h2[t3]
                const int g2 = i*512 + tid;
                const int lb = g2 >> 7, r = g2 & 127, q = r >> 1, hf = r & 1;
                u64 vv = aload8(h2buf + (size_t)sH*BH + (size_t)(bhalf*32 + lb)*H_ + ((q ^ (lb & 7))*8 + hf*4));
                *(u64*)(smem + H1S_OFF + (size_t)(lb*64 + q)*16 + hf*8) = vv;
            }
            __syncthreads();   // staging drained -> release back-pressure
            if (tid == 0) flag_add(aH + t3);
            floatx4 acc0 = {0.f,0.f,0.f,0.f}, acc1 = {0.f,0.f,0.f,0.f};
            #pragma unroll
            for (int k = 0; k < 8; ++k) {
                const int kc = (kh*8 + k)*4 + quad;
                half8 a0 = *(const half8*)(smem + H1S_OFF + ((size_t)lb0*64 + (kc ^ swz))*16);
                half8 a1v = *(const half8*)(smem + H1S_OFF + ((size_t)lb1*64 + (kc ^ swz))*16);
                acc0 = MFMA16(a0,  wr[k], acc0);
                acc1 = MFMA16(a1v, wr[k], acc1);
            }
            if (kh == 1) {
                #pragma unroll
                for (int r = 0; r < 4; ++r) {
                    RED[(nt*2+0)*256 + (quad*4 + r)*16 + col] = acc0[r];
                    RED[(nt*2+1)*256 + (quad*4 + r)*16 + col] = acc1[r];
                }
            }
            __syncthreads();
            if (kh == 0) {
                #pragma unroll
                for (int r = 0; r < 4; ++r) {
                    const float v0 = acc0[r] + RED[(nt*2+0)*256 + (quad*4 + r)*16 + col] + boutr;
                    const float v1 = acc1[r] + RED[(nt*2+1)*256 + (quad*4 + r)*16 + col] + boutr;
                    const int b0 = bhalf*32 +  0 + quad*4 + r;
                    const int b1 = bhalf*32 + 16 + quad*4 + r;
                    y[((size_t)b0*T_ + t3)*OUT_ + nt*16 + col] = v0;
                    y[((size_t)b1*T_ + t3)*OUT_ + nt*16 + col] = v1;
                }
            }
            __syncthreads();   // RED reuse next step
        }
    }
}

// ---------------- launch ----------------
extern "C" void kernel_launch(void* const* d_in, const int* in_sizes, int n_in,
                              void* d_out, int out_size, void* d_ws, size_t ws_size,
                              hipStream_t stream) {
    const float* x    = (const float*)d_in[0];
    const float* Wih1 = (const float*)d_in[1];
    const float* Whh1 = (const float*)d_in[2];
    const float* bih1 = (const float*)d_in[3];
    const float* bhh1 = (const float*)d_in[4];
    const float* Wih2 = (const float*)d_in[5];
    const float* Whh2 = (const float*)d_in[6];
    const float* bih2 = (const float*)d_in[7];
    const float* bhh2 = (const float*)d_in[8];
    const float* Wout = (const float*)d_in[9];
    const float* bout = (const float*)d_in[10];
    float* y = (float*)d_out;

    char* ws = (char*)d_ws;
    f16*   W1p   = (f16*)(ws + 0);           // 2,359,296 B
    f16*   W2p   = (f16*)(ws + 2359296);     // 4,194,304 B
    f16*   Wop   = (f16*)(ws + 6553600);     //    65,536 B
    float* bs1   = (float*)(ws + 6619136);   //     8,192 B
    float* bs2   = (float*)(ws + 6627328);   //     8,192 B
    f16*   h1buf = (f16*)(ws + 6635520);     // 8 slots = 524,288 B
    f16*   h2buf = (f16*)(ws + 7159808);     // 8 slots = 524,288 B
    u32*   arr1  = (u32*)(ws + 7684096);     //     8,192 B
    u32*   arr2  = (u32*)(ws + 7692288);     //     8,192 B
    u32*   arrH  = (u32*)(ws + 7700480);     //     8,192 B

    // zero h slots (t=-1 state lives in slot 7) + all arrival counters
    hipMemsetAsync(ws + 6635520, 0, 1073152, stream);

    pack_w1<<<4608, 256, 0, stream>>>(Wih1, Whh1, W1p);
    pack_w2<<<8192, 256, 0, stream>>>(Wih2, Whh2, W2p);
    pack_wo<<<128, 256, 0, stream>>>(Wout, Wop);
    bias_sum<<<8, 256, 0, stream>>>(bih1, bhh1, bih2, bhh2, bs1, bs2);

    lstm_persist<<<NWG, 512, 0, stream>>>(x, W1p, W2p, Wop, bs1, bs2, bout,
                                          h1buf, h2buf, y, arr1, arr2, arrH);
}

// Round 4
// 4754.258 us; speedup vs baseline: 1.5036x; 1.5036x over previous
//
#include <hip/hip_runtime.h>

#define B_    64
#define T_    1024
#define IN_   64
#define H_    512
#define OUT_  64
#define SLOTS 8
#define NWG   130
#define NWORD 6144      // words per (bhalf, slot): 32 jt * 32 rows * 6 words

typedef _Float16 f16;
typedef _Float16 half8 __attribute__((ext_vector_type(8)));
typedef float    floatx4 __attribute__((ext_vector_type(4)));
typedef unsigned int u32;
typedef unsigned short u16;
typedef unsigned long long u64;

#define MFMA16(a,b,c) __builtin_amdgcn_mfma_f32_16x16x32_f16((a),(b),(c),0,0,0)

// LDS layout (158720 B, 1 WG/CU)
// H1W/H2W hold RAW tagged words [jt][row][7] (row stride 7 u64 = 56B -> 16-bank spread)
#define XS_OFF   0        // 8KB: L1 x-stage (dense fp32, swizzled as R5)
#define HB_OFF   8192     // 1KB: pointwise h output (f16[512])
#define CC_OFF   9216     // 2KB: c-state
#define RED_OFF  11264    // 32KB: 4 kq-regions x 8KB partial-sum
#define H1W_OFF  44032    // 57344: packed h words (h1 for L1/L2; h2 for head)
#define H2W_OFF  101376   // 57344: packed h2 words (L2 pass B)

__device__ __forceinline__ float sigmoidf_(float x) {
    return 1.0f / (1.0f + __expf(-x));
}
__device__ __forceinline__ float tanhf_(float x) {
    float ax = fabsf(x);
    float e  = __expf(-2.0f * ax);
    float t  = (1.0f - e) / (1.0f + e);
    return x >= 0.0f ? t : -t;
}

// Flags: agent-scope RMW + agent-scope poll (proven R2/R5). Back-pressure edges only.
__device__ __forceinline__ void wait_ge(u32* p, u32 v) {
    while (__hip_atomic_load(p, __ATOMIC_RELAXED, __HIP_MEMORY_SCOPE_AGENT) < v)
        __builtin_amdgcn_s_sleep(1);
}
__device__ __forceinline__ void flag_add(u32* p) {
    __hip_atomic_fetch_add(p, 1u, __ATOMIC_RELAXED, __HIP_MEMORY_SCOPE_AGENT);
}
// Tagged-word publish: relaxed system-scope atomic store. Tag is IN the word ->
// no ordering vs anything else is needed; word is self-validating.
__device__ __forceinline__ void astore8w(u64* p, u64 v) {
    __hip_atomic_store(p, v, __ATOMIC_RELAXED, __HIP_MEMORY_SCOPE_SYSTEM);
}
__device__ __forceinline__ u64 aload8w(const u64* p) {
    return __hip_atomic_load(p, __ATOMIC_RELAXED, __HIP_MEMORY_SCOPE_SYSTEM);
}

// Poll-stage one 49KB tagged buffer (6144 words) into LDS raw-word layout.
// Each thread owns 12 lane-coalesced words; re-loads all 12 per round (branch-free
// load batch), commits those whose tag matches. soff[i] precomputed per thread.
__device__ __forceinline__ void stage_poll(char* smem, int ldsOff, const u64* g,
                                           u32 exp, int tid, const int* soff) {
    u32 pend = 0xFFFu;
    do {
        u64 vv[12];
        #pragma unroll
        for (int i = 0; i < 12; ++i)
            vv[i] = aload8w(g + i*512 + tid);
        #pragma unroll
        for (int i = 0; i < 12; ++i) {
            if ((pend & (1u << i)) && (u32)(vv[i] >> 48) == exp) {
                *(u64*)(smem + ldsOff + soff[i]) = vv[i];
                pend &= ~(1u << i);
            }
        }
        if (pend) __builtin_amdgcn_s_sleep(1);
    } while (pend);
}

// Build a half8 fragment (8 consecutive k-values) from 3 packed LDS words.
__device__ __forceinline__ half8 frag_pk(const char* p) {
    const u64* q = (const u64*)p;
    u64 w0 = q[0], w1 = q[1], w2 = q[2];
    u32 b = (u32)(w0 >> 32), c = (u32)w1, d = (u32)(w1 >> 32);
    union { u32 u[4]; half8 h; } U;
    U.u[0] = (u32)w0;
    U.u[1] = (b & 0xffffu) | (c << 16);
    U.u[2] = (c >> 16) | (d << 16);
    U.u[3] = (u32)w2;
    return U.h;
}
// LDS byte offset of word (jt, row, wi): ((jt*32+row)*7 + wi)*8
#define WB(jt,row,wi) (((jt)*224 + (row)*7 + (wi)) * 8)

// ---------------- prep kernels (weights -> fp16 fragment-linear) ----------------
__global__ void pack_w1(const float* __restrict__ Wih, const float* __restrict__ Whh,
                        f16* __restrict__ Wp) {
    int idx = blockIdx.x * 256 + threadIdx.x;
    if (idx >= 4*32*18*512) return;
    int j    = idx & 7;
    int lane = (idx >> 3) & 63;
    int kt   = (idx >> 9) % 18;
    int r    = (idx >> 9) / 18;
    int jt   = r & 31;
    int g    = r >> 5;
    int n = g*512 + jt*16 + (lane & 15);
    int k = kt*32 + (lane >> 4)*8 + j;
    float v = (k < 64) ? Wih[n*64 + k] : Whh[n*512 + (k - 64)];
    Wp[idx] = (f16)v;
}

__global__ void pack_w2(const float* __restrict__ Wih, const float* __restrict__ Whh,
                        f16* __restrict__ Wp) {
    int idx = blockIdx.x * 256 + threadIdx.x;
    if (idx >= 4*32*32*512) return;
    int j    = idx & 7;
    int lane = (idx >> 3) & 63;
    int kt   = (idx >> 9) & 31;
    int r    = idx >> 14;
    int jt   = r & 31;
    int g    = r >> 5;
    int n = g*512 + jt*16 + (lane & 15);
    int k = kt*32 + (lane >> 4)*8 + j;
    float v = (k < 512) ? Wih[n*512 + k] : Whh[n*512 + (k - 512)];
    Wp[idx] = (f16)v;
}

__global__ void pack_wo(const float* __restrict__ Wout, f16* __restrict__ Wp) {
    int idx = blockIdx.x * 256 + threadIdx.x;
    if (idx >= 4*16*512) return;
    int j    = idx & 7;
    int lane = (idx >> 3) & 63;
    int kt   = (idx >> 9) & 15;
    int nt   = idx >> 13;
    int n = nt*16 + (lane & 15);
    int k = kt*32 + (lane >> 4)*8 + j;
    Wp[idx] = (f16)Wout[n*512 + k];
}

__global__ void bias_sum(const float* __restrict__ a1, const float* __restrict__ b1,
                         const float* __restrict__ a2, const float* __restrict__ b2,
                         float* __restrict__ s1, float* __restrict__ s2) {
    int i = blockIdx.x * 256 + threadIdx.x;
    if (i >= 2048) return;
    s1[i] = a1[i] + b1[i];
    s2[i] = a2[i] + b2[i];
}

// ---------------- persistent self-timed kernel ----------------
// R9: tagged-word dataflow. h buffers are u64 words [slot][bhalf][jt][row][6]:
// word = v0 | v1<<16 | v2<<32 | (step+1)<<48  (3 f16 per word; row of 16 cols =
// 2 octets x 3 words: cols {0-2,3-5,6-7} per octet). Consumers poll the words
// themselves; no data-ready flags. Flags kept only for slot back-pressure:
// arr2[t]=32 -> L2 done step t (guards L1 overwriting h1 slot t&7);
// arrH[t]=1  -> head staged h2[t]  (guards L2 overwriting h2 slot t&7).
__global__ __launch_bounds__(512, 1) void lstm_persist(
    const float* __restrict__ x,
    const f16*  __restrict__ W1p,
    const f16*  __restrict__ W2p,
    const f16*  __restrict__ Wop,
    const float* __restrict__ bs1,
    const float* __restrict__ bs2,
    const float* __restrict__ bout,
    u64*  __restrict__ h1w,     // [8][2][6144] tagged words
    u64*  __restrict__ h2w,     // [8][2][6144]
    float* __restrict__ y,
    u32*  __restrict__ arr2,    // [2][1024]
    u32*  __restrict__ arrH)    // [2][1024]
{
    __shared__ __align__(16) char smem[158720];
    float* RED = (float*)(smem + RED_OFF);
    float* CC  = (float*)(smem + CC_OFF);

    const int wg   = blockIdx.x;
    const int tid  = threadIdx.x;
    const int lane = tid & 63;
    const int w    = tid >> 6;
    const int col  = lane & 15;
    const int quad = lane >> 4;

    // staging LDS offsets for this thread's 12 words
    int soff[12];
    #pragma unroll
    for (int i = 0; i < 12; ++i) {
        const int ww = i*512 + tid;
        const int jt_ = ww / 192, rr = ww - jt_*192;
        soff[i] = WB(jt_, rr/6, rr%6);
    }
    // publisher params (valid for tid<192): word tid = r*6 + i of own slice
    const int pr  = tid / 6, pi = tid - pr*6;
    const int pj  = pi % 3;
    const int pc0 = pr*16 + (pi/3)*8 + pj*3;   // first col of this word
    const u16* hb = (const u16*)(smem + HB_OFF);

    if (wg < 64) {
        // ================= layer 1 =================
        const int jt = wg & 31, bhalf = wg >> 5;
        const int gp = w & 1, kq = w >> 1;
        half8 wrx[2];
        half8 wrh[2][4];
        if (kq < 2) {
            #pragma unroll
            for (int gi = 0; gi < 2; ++gi)
                wrx[gi] = *(const half8*)(W1p + ((size_t)(((gp*2+gi)*32 + jt)*18 + kq)*64 + lane)*8);
        }
        #pragma unroll
        for (int gi = 0; gi < 2; ++gi)
            #pragma unroll
            for (int k = 0; k < 4; ++k) {
                const int kt = 2 + kq*4 + k;
                wrh[gi][k] = *(const half8*)(W1p + ((size_t)(((gp*2+gi)*32 + jt)*18 + kt)*64 + lane)*8);
            }
        float bsr[4];
        #pragma unroll
        for (int g = 0; g < 4; ++g) bsr[g] = bs1[g*512 + jt*16 + (tid & 15)];
        CC[tid] = 0.f;

        u32* a2 = arr2 + bhalf*1024;

        // prologue: x_0 + h1[-1] (slot 7, tag 0 = zeroed buffer)
        {
            const int lb = tid >> 4, kc4 = tid & 15;
            const float* src = x + ((size_t)(bhalf*32 + lb)*T_ + 0)*(size_t)IN_ + ((kc4 ^ (lb & 7)) * 4);
            *(float4*)(smem + XS_OFF + tid*16) = *(const float4*)src;
        }
        stage_poll(smem, H1W_OFF, h1w + (size_t)(7*2 + bhalf)*NWORD, 0u, tid, soff);
        __syncthreads();

        for (int t = 0; t < T_; ++t) {
            floatx4 acc[2][2] = {{{0.f,0.f,0.f,0.f},{0.f,0.f,0.f,0.f}},
                                 {{0.f,0.f,0.f,0.f},{0.f,0.f,0.f,0.f}}};
            #pragma unroll
            for (int m = 0; m < 2; ++m) {
                const int lb_a = m*16 + col, sw = lb_a & 7;
                if (kq < 2) {   // x-part: this kq's 32-col tile
                    const int fg = kq*8 + quad*2;
                    float4 u = *(const float4*)(smem + XS_OFF + ((size_t)lb_a*16 + (fg ^ sw))*16);
                    float4 v = *(const float4*)(smem + XS_OFF + ((size_t)lb_a*16 + ((fg+1) ^ sw))*16);
                    half8 a = (half8){(f16)u.x,(f16)u.y,(f16)u.z,(f16)u.w,
                                      (f16)v.x,(f16)v.y,(f16)v.z,(f16)v.w};
                    acc[0][m] = MFMA16(a, wrx[0], acc[0][m]);
                    acc[1][m] = MFMA16(a, wrx[1], acc[1][m]);
                }
                #pragma unroll
                for (int k = 0; k < 4; ++k) {
                    const int kc = kq*16 + k*4 + quad;
                    half8 a = frag_pk(smem + H1W_OFF + WB(kc>>1, lb_a, (kc&1)*3));
                    acc[0][m] = MFMA16(a, wrh[0][k], acc[0][m]);
                    acc[1][m] = MFMA16(a, wrh[1][k], acc[1][m]);
                }
            }
            #pragma unroll
            for (int gi = 0; gi < 2; ++gi) {
                const int g = gp*2 + gi;
                #pragma unroll
                for (int m = 0; m < 2; ++m)
                    #pragma unroll
                    for (int r = 0; r < 4; ++r)
                        RED[kq*2048 + g*512 + (m*16 + quad*4 + r)*16 + col] = acc[gi][m][r];
            }
            __syncthreads();
            {   // 4-way kq sum + pointwise -> HB
                float gt[4];
                #pragma unroll
                for (int g = 0; g < 4; ++g)
                    gt[g] = RED[       g*512 + tid] + RED[2048 + g*512 + tid]
                          + RED[4096 + g*512 + tid] + RED[6144 + g*512 + tid] + bsr[g];
                const float i_ = sigmoidf_(gt[0]);
                const float f_ = sigmoidf_(gt[1]);
                const float g_ = tanhf_(gt[2]);
                const float o_ = sigmoidf_(gt[3]);
                const float cn = f_ * CC[tid] + i_ * g_;
                CC[tid] = cn;
                ((f16*)(smem + HB_OFF))[tid] = (f16)(o_ * tanhf_(cn));
            }
            __syncthreads();
            // publish h1[t] (tagged words, one-way stores) -- earliest possible
            if (tid < 192) {
                u64 wv = (u64)hb[pc0] | ((u64)hb[pc0+1] << 16)
                       | ((pj < 2) ? ((u64)hb[pc0+2] << 32) : 0)
                       | ((u64)(u32)(t + 1) << 48);
                astore8w(h1w + (size_t)((t & 7)*2 + bhalf)*NWORD + jt*192 + tid, wv);
            }
            // back-pressure for NEXT publish (slot reuse): L2 done reading h1[t-7]
            if (tid == 0 && t + 1 < T_ && t + 1 >= SLOTS)
                wait_ge(a2 + (t + 1 - SLOTS), 32u);
            if (t + 1 < T_) {
                {   // stage x_{t+1} (plain loads; XS free after MFMA barriers)
                    const int lb = tid >> 4, kc4 = tid & 15;
                    const float* src = x + ((size_t)(bhalf*32 + lb)*T_ + (t+1))*(size_t)IN_ + ((kc4 ^ (lb & 7)) * 4);
                    *(float4*)(smem + XS_OFF + tid*16) = *(const float4*)src;
                }
                // stage h1[t] (just published by self + 31 peers): the poll IS the sync
                stage_poll(smem, H1W_OFF, h1w + (size_t)((t & 7)*2 + bhalf)*NWORD,
                           (u32)(t + 1), tid, soff);
            }
            __syncthreads();   // staged data ready; store-acks drain hidden behind poll
        }
    } else if (wg < 128) {
        // ================= layer 2 =================
        const int v = wg - 64;
        const int jt = v & 31, bhalf = v >> 5;
        const int gp = w & 1, kq = w >> 1;
        half8 wrA[2][4], wrB[2][4];
        #pragma unroll
        for (int gi = 0; gi < 2; ++gi)
            #pragma unroll
            for (int k = 0; k < 4; ++k) {
                const int ktA = kq*4 + k;        // h1 half (K 0..511)
                const int ktB = 16 + kq*4 + k;   // h2 half (K 512..1023)
                wrA[gi][k] = *(const half8*)(W2p + ((size_t)(((gp*2+gi)*32 + jt)*32 + ktA)*64 + lane)*8);
                wrB[gi][k] = *(const half8*)(W2p + ((size_t)(((gp*2+gi)*32 + jt)*32 + ktB)*64 + lane)*8);
            }
        float bsr[4];
        #pragma unroll
        for (int g = 0; g < 4; ++g) bsr[g] = bs2[g*512 + jt*16 + (tid & 15)];
        CC[tid] = 0.f;

        u32* a2 = arr2 + bhalf*1024;
        u32* aH = arrH + bhalf*1024;

        // prologue: h1[0] (tag 1, spins until L1 publishes) + h2[-1] (slot 7, tag 0)
        stage_poll(smem, H1W_OFF, h1w + (size_t)(0*2 + bhalf)*NWORD, 1u, tid, soff);
        stage_poll(smem, H2W_OFF, h2w + (size_t)(7*2 + bhalf)*NWORD, 0u, tid, soff);
        __syncthreads();

        for (int t2 = 0; t2 < T_; ++t2) {
            floatx4 acc[2][2] = {{{0.f,0.f,0.f,0.f},{0.f,0.f,0.f,0.f}},
                                 {{0.f,0.f,0.f,0.f},{0.f,0.f,0.f,0.f}}};
            #pragma unroll
            for (int m = 0; m < 2; ++m) {   // pass A (h1[t2])
                const int lb_a = m*16 + col;
                #pragma unroll
                for (int k = 0; k < 4; ++k) {
                    const int kc = kq*16 + k*4 + quad;
                    half8 a = frag_pk(smem + H1W_OFF + WB(kc>>1, lb_a, (kc&1)*3));
                    acc[0][m] = MFMA16(a, wrA[0][k], acc[0][m]);
                    acc[1][m] = MFMA16(a, wrA[1][k], acc[1][m]);
                }
            }
            #pragma unroll
            for (int m = 0; m < 2; ++m) {   // pass B (h2[t2-1])
                const int lb_a = m*16 + col;
                #pragma unroll
                for (int k = 0; k < 4; ++k) {
                    const int kc = kq*16 + k*4 + quad;
                    half8 a = frag_pk(smem + H2W_OFF + WB(kc>>1, lb_a, (kc&1)*3));
                    acc[0][m] = MFMA16(a, wrB[0][k], acc[0][m]);
                    acc[1][m] = MFMA16(a, wrB[1][k], acc[1][m]);
                }
            }
            #pragma unroll
            for (int gi = 0; gi < 2; ++gi) {
                const int g = gp*2 + gi;
                #pragma unroll
                for (int m = 0; m < 2; ++m)
                    #pragma unroll
                    for (int r = 0; r < 4; ++r)
                        RED[kq*2048 + g*512 + (m*16 + quad*4 + r)*16 + col] = acc[gi][m][r];
            }
            __syncthreads();
            {   // 4-way kq sum + pointwise -> HB
                float gt[4];
                #pragma unroll
                for (int g = 0; g < 4; ++g)
                    gt[g] = RED[       g*512 + tid] + RED[2048 + g*512 + tid]
                          + RED[4096 + g*512 + tid] + RED[6144 + g*512 + tid] + bsr[g];
                const float i_ = sigmoidf_(gt[0]);
                const float f_ = sigmoidf_(gt[1]);
                const float g_ = tanhf_(gt[2]);
                const float o_ = sigmoidf_(gt[3]);
                const float cn = f_ * CC[tid] + i_ * g_;
                CC[tid] = cn;
                ((f16*)(smem + HB_OFF))[tid] = (f16)(o_ * tanhf_(cn));
            }
            __syncthreads();
            // publish h2[t2] -- earliest possible, one-way stores
            if (tid < 192) {
                u64 wv = (u64)hb[pc0] | ((u64)hb[pc0+1] << 16)
                       | ((pj < 2) ? ((u64)hb[pc0+2] << 32) : 0)
                       | ((u64)(u32)(t2 + 1) << 48);
                astore8w(h2w + (size_t)((t2 & 7)*2 + bhalf)*NWORD + jt*192 + tid, wv);
            }
            // done reading h1[t2] & h2[t2-1]: release L1's slot guard
            if (tid == 0) flag_add(a2 + t2);
            // back-pressure for NEXT publish: head staged h2[t2-7]
            if (tid == 0 && t2 + 1 < T_ && t2 + 1 >= SLOTS)
                wait_ge(aH + (t2 + 1 - SLOTS), 1u);
            if (t2 + 1 < T_) {
                stage_poll(smem, H1W_OFF, h1w + (size_t)(((t2+1) & 7)*2 + bhalf)*NWORD,
                           (u32)(t2 + 2), tid, soff);
                stage_poll(smem, H2W_OFF, h2w + (size_t)((t2 & 7)*2 + bhalf)*NWORD,
                           (u32)(t2 + 1), tid, soff);
            }
            __syncthreads();
        }
    } else {
        // ================= head =================
        const int bhalf = wg - 128;
        const int nt = w & 3, kh = w >> 2;
        half8 wr[8];
        #pragma unroll
        for (int k = 0; k < 8; ++k) {
            const int kt = kh*8 + k;
            wr[k] = *(const half8*)(Wop + ((size_t)(nt*16 + kt)*64 + lane)*8);
        }
        const float boutr = bout[nt*16 + col];
        u32* aH = arrH + bhalf*1024;
        const int lb0 = col, lb1 = 16 + col;

        // prologue: stage h2[0]
        stage_poll(smem, H1W_OFF, h2w + (size_t)(0*2 + bhalf)*NWORD, 1u, tid, soff);
        __syncthreads();
        if (tid == 0) flag_add(aH + 0);

        for (int t3 = 0; t3 < T_; ++t3) {
            floatx4 acc0 = {0.f,0.f,0.f,0.f}, acc1 = {0.f,0.f,0.f,0.f};
            #pragma unroll
            for (int k = 0; k < 8; ++k) {
                const int kc = (kh*8 + k)*4 + quad;
                half8 a0  = frag_pk(smem + H1W_OFF + WB(kc>>1, lb0, (kc&1)*3));
                half8 a1v = frag_pk(smem + H1W_OFF + WB(kc>>1, lb1, (kc&1)*3));
                acc0 = MFMA16(a0,  wr[k], acc0);
                acc1 = MFMA16(a1v, wr[k], acc1);
            }
            if (kh == 1) {
                #pragma unroll
                for (int r = 0; r < 4; ++r) {
                    RED[(nt*2+0)*256 + (quad*4 + r)*16 + col] = acc0[r];
                    RED[(nt*2+1)*256 + (quad*4 + r)*16 + col] = acc1[r];
                }
            }
            __syncthreads();
            if (kh == 0) {
                #pragma unroll
                for (int r = 0; r < 4; ++r) {
                    const float v0 = acc0[r] + RED[(nt*2+0)*256 + (quad*4 + r)*16 + col] + boutr;
                    const float v1 = acc1[r] + RED[(nt*2+1)*256 + (quad*4 + r)*16 + col] + boutr;
                    const int b0 = bhalf*32 +  0 + quad*4 + r;
                    const int b1 = bhalf*32 + 16 + quad*4 + r;
                    y[((size_t)b0*T_ + t3)*OUT_ + nt*16 + col] = v0;
                    y[((size_t)b1*T_ + t3)*OUT_ + nt*16 + col] = v1;
                }
            }
            __syncthreads();   // RED reuse
            if (t3 + 1 < T_) {
                stage_poll(smem, H1W_OFF, h2w + (size_t)(((t3+1) & 7)*2 + bhalf)*NWORD,
                           (u32)(t3 + 2), tid, soff);
                __syncthreads();               // staging complete
                if (tid == 0) flag_add(aH + (t3 + 1));   // release L2's slot guard
            }
        }
    }
}

// ---------------- launch ----------------
extern "C" void kernel_launch(void* const* d_in, const int* in_sizes, int n_in,
                              void* d_out, int out_size, void* d_ws, size_t ws_size,
                              hipStream_t stream) {
    const float* x    = (const float*)d_in[0];
    const float* Wih1 = (const float*)d_in[1];
    const float* Whh1 = (const float*)d_in[2];
    const float* bih1 = (const float*)d_in[3];
    const float* bhh1 = (const float*)d_in[4];
    const float* Wih2 = (const float*)d_in[5];
    const float* Whh2 = (const float*)d_in[6];
    const float* bih2 = (const float*)d_in[7];
    const float* bhh2 = (const float*)d_in[8];
    const float* Wout = (const float*)d_in[9];
    const float* bout = (const float*)d_in[10];
    float* y = (float*)d_out;

    char* ws = (char*)d_ws;
    f16*   W1p   = (f16*)(ws + 0);           // 2,359,296 B
    f16*   W2p   = (f16*)(ws + 2359296);     // 4,194,304 B
    f16*   Wop   = (f16*)(ws + 6553600);     //    65,536 B
    float* bs1   = (float*)(ws + 6619136);   //     8,192 B
    float* bs2   = (float*)(ws + 6627328);   //     8,192 B
    u64*   h1w   = (u64*)(ws + 6635520);     //   786,432 B (8 slots x 2 bh x 6144 words)
    u64*   h2w   = (u64*)(ws + 7421952);     //   786,432 B
    u32*   arr2  = (u32*)(ws + 8208384);     //     8,192 B
    u32*   arrH  = (u32*)(ws + 8216576);     //     8,192 B

    // zero tagged-word buffers (tag 0 = step -1 state) + back-pressure counters
    hipMemsetAsync(ws + 6635520, 0, 1589248, stream);

    pack_w1<<<4608, 256, 0, stream>>>(Wih1, Whh1, W1p);
    pack_w2<<<8192, 256, 0, stream>>>(Wih2, Whh2, W2p);
    pack_wo<<<128, 256, 0, stream>>>(Wout, Wop);
    bias_sum<<<8, 256, 0, stream>>>(bih1, bhh1, bih2, bhh2, bs1, bs2);

    lstm_persist<<<NWG, 512, 0, stream>>>(x, W1p, W2p, Wop, bs1, bs2, bout,
                                          h1w, h2w, y, arr2, arrH);
}